// Round 15
// baseline (220.649 us; speedup 1.0000x reference)
//
#include <hip/hip_runtime.h>
#include <hip/hip_fp16.h>
#include <math.h>

#define HH    512
#define DICT  8192
#define BATCH 4096
#define NCYC  10
#define DTT   0.6f

#define BM  128
#define BKT 64

using f16x8 = __attribute__((ext_vector_type(8))) _Float16;
using f32x4 = __attribute__((ext_vector_type(4))) float;

__device__ __forceinline__ float sigmoidf_(float x) { return 1.0f / (1.0f + __expf(-x)); }

__device__ __forceinline__ float waveReduceSum(float v) {
#pragma unroll
  for (int o = 1; o < 64; o <<= 1) v += __shfl_xor(v, o);
  return v;
}

__device__ __forceinline__ void gld16(const void* g, void* l) {
  __builtin_amdgcn_global_load_lds(
      (const __attribute__((address_space(1))) void*)g,
      (__attribute__((address_space(3))) void*)l, 16, 0, 0);
}

template<int N> __device__ __forceinline__ void vmwait() {
  if constexpr (N == 8)      asm volatile("s_waitcnt vmcnt(8)" ::: "memory");
  else if constexpr (N == 6) asm volatile("s_waitcnt vmcnt(6)" ::: "memory");
  else if constexpr (N == 2) asm volatile("s_waitcnt vmcnt(2)" ::: "memory");
  else                       asm volatile("s_waitcnt vmcnt(0)" ::: "memory");
  __builtin_amdgcn_sched_barrier(0);
}

__device__ __forceinline__ void blockbar() {
  asm volatile("" ::: "memory");
  __builtin_amdgcn_s_barrier();
  __builtin_amdgcn_sched_barrier(0);
}

// ======== BKT=64 machinery (256-thread kernels: preact, a2c, mt_p) ========
template<int ROWS>
__device__ __forceinline__ void stage_tile(const __half* gbase, int ld, char* lds, int tid) {
  constexpr int ISS = ROWS * 8 / 256;
#pragma unroll
  for (int i = 0; i < ISS; ++i) {
    int cidx = i * 256 + tid;
    int row  = cidx >> 3;
    int slot = cidx & 7;
    int k4   = slot ^ (row & 7);
    gld16(gbase + (size_t)row * ld + k4 * 8, lds + cidx * 16);
  }
}

__device__ __forceinline__ f16x8 frag_ld(const char* lds, int row, int kchunk) {
  int slot = kchunk ^ (row & 7);
  return *(const f16x8*)(lds + row * 128 + slot * 16);
}

template<int FN>
__device__ __forceinline__ void tile_mfma(const char* As, const char* Bs,
                                          int lane, int wr, int wc, f32x4 (&acc)[4][FN]) {
  const int g = lane >> 4, r = lane & 15;
#pragma unroll
  for (int ks = 0; ks < 2; ++ks) {
    f16x8 af[4], bfr[FN];
#pragma unroll
    for (int i = 0; i < 4; ++i)
      af[i] = frag_ld(As, wr * 64 + i * 16 + r, ks * 4 + g);
#pragma unroll
    for (int j = 0; j < FN; ++j)
      bfr[j] = frag_ld(Bs, wc * (FN * 16) + j * 16 + r, ks * 4 + g);
#pragma unroll
    for (int i = 0; i < 4; ++i)
#pragma unroll
      for (int j = 0; j < FN; ++j)
        acc[i][j] = __builtin_amdgcn_mfma_f32_16x16x32_f16(af[i], bfr[j], acc[i][j], 0, 0, 0);
  }
}

template<int BN, int FN>
__device__ __forceinline__ void gemm_seg(const __half* A, int lda, const __half* B, int ldb,
                                         int m0, int n0, int K, char* lds, int tid,
                                         f32x4 (&acc)[4][FN]) {
  constexpr int ABYTES = BM * BKT * 2;
  constexpr int BBYTES = BN * BKT * 2;
  constexpr int BUF = ABYTES + BBYTES;
  constexpr int NL = (BM + BN) * 8 / 256;
  const int lane = tid & 63, wid = tid >> 6;
  const int wr = wid >> 1, wc = wid & 1;
  const int nt = K / BKT;
  const __half* Ab = A + (size_t)m0 * lda;
  const __half* Bb = B + (size_t)n0 * ldb;
  stage_tile<BM>(Ab, lda, lds, tid);
  stage_tile<BN>(Bb, ldb, lds + ABYTES, tid);
  int cur = 0;
  for (int t = 0; t < nt; ++t) {
    char* curb = lds + cur * BUF;
    if (t + 1 < nt) {
      char* nxt = lds + (cur ^ 1) * BUF;
      stage_tile<BM>(Ab + (t + 1) * BKT, lda, nxt, tid);
      stage_tile<BN>(Bb + (t + 1) * BKT, ldb, nxt + ABYTES, tid);
      vmwait<NL>();
    } else {
      vmwait<0>();
    }
    blockbar();
    tile_mfma<FN>(curb, curb + ABYTES, lane, wr, wc, acc);
    blockbar();
    cur ^= 1;
  }
}

__device__ __forceinline__ void zero_acc4(f32x4 (&a)[4][4]) {
  f32x4 z = {0.f, 0.f, 0.f, 0.f};
#pragma unroll
  for (int i = 0; i < 4; ++i)
#pragma unroll
    for (int j = 0; j < 4; ++j) a[i][j] = z;
}
__device__ __forceinline__ void zero_acc2(f32x4 (&a)[4][2]) {
  f32x4 z = {0.f, 0.f, 0.f, 0.f};
#pragma unroll
  for (int i = 0; i < 4; ++i)
#pragma unroll
    for (int j = 0; j < 2; ++j) a[i][j] = z;
}

// ======== 8-phase 256x256 machinery (512-thread kernel: sim) ========
__device__ __forceinline__ void stage_half(const __half* tilebase, int ld, char* ldstile,
                                           int h, int kcol, int tid) {
#pragma unroll
  for (int i = 0; i < 2; ++i) {
    int cidx = i * 512 + tid;
    int lrow = cidx >> 3;
    int slot = cidx & 7;
    int row  = h * 128 + lrow;
    int k4   = slot ^ (row & 7);
    gld16(tilebase + (size_t)row * ld + kcol + k4 * 8,
          ldstile + row * 128 + slot * 16);
  }
}

__device__ __forceinline__ f16x8 fragA8(const char* At, int fi, int wr, int ks, int lane) {
  int r = lane & 15, g = lane >> 4;
  int row = fi * 32 + wr * 16 + r;
  int slot = (ks * 4 + g) ^ (row & 7);
  return *(const f16x8*)(At + row * 128 + slot * 16);
}
__device__ __forceinline__ f16x8 fragB8(const char* Bt, int j, int wc, int ks, int lane) {
  int r = lane & 15, g = lane >> 4;
  int row = wc * 64 + j * 16 + r;
  int slot = (ks * 4 + g) ^ (row & 7);
  return *(const f16x8*)(Bt + row * 128 + slot * 16);
}

#define PHASE(TT, KS, MH, RB)                                                  \
  {                                                                            \
    if (RB) {                                                                  \
      _Pragma("unroll")                                                        \
      for (int j = 0; j < 4; ++j) bf[j] = fragB8((TT) + 32768, j, wc, KS, lane); \
    }                                                                          \
    f16x8 af[4];                                                               \
    _Pragma("unroll")                                                          \
    for (int i = 0; i < 4; ++i) af[i] = fragA8((TT), (MH)*4 + i, wr, KS, lane); \
    __builtin_amdgcn_s_setprio(1);                                             \
    _Pragma("unroll")                                                          \
    for (int i = 0; i < 4; ++i)                                                \
      _Pragma("unroll")                                                        \
      for (int j = 0; j < 4; ++j)                                              \
        acc[(MH)*4 + i][j] = __builtin_amdgcn_mfma_f32_16x16x32_f16(           \
            af[i], bf[j], acc[(MH)*4 + i][j], 0, 0, 0);                        \
    __builtin_amdgcn_s_setprio(0);                                             \
  }

// 8-phase loop with MINIMAL barriers (4/iter instead of 8). Hazard ledger:
//  G1 = {ph0,ph1,ph2}: all writes -> b1, all reads -> b0 (disjoint, no bar).
//  bar after ph2: ph3's... ph3-group (G2) stages b0h0 (WAR vs ph0/ph2 reads
//    of b0 rows 0-127).
//  vmwait + bar after ph3: G3 stages b0h1 (WAR vs ph1/ph3 reads of b0 rows
//    128-255) and reads b1 (RAW: vmcnt(2) leaves only G2's 2 loads in flight,
//    so prologue/G1's b1 stages are landed).
//  G3 = {ph4,ph5,ph6}: writes -> b0, reads -> b1 (disjoint).
//  bar after ph6: ph7 stages b1h0 (WAR vs ph4/ph6 reads of b1 rows 0-127).
//  vmwait + bar at loop head: next ph0 stages b1h1 (WAR vs ph5/ph7 reads) and
//    reads b0 (RAW: vmcnt(2) leaves only G4's 2 loads).
template<int NT>
__device__ __forceinline__ void gemm_8ph(const __half* At, int lda,
                                         const __half* Bt, int ldb,
                                         char* lds, int tid, f32x4 (&acc)[8][4]) {
  const int lane = tid & 63, wid = tid >> 6;
  const int wr = wid >> 2, wc = wid & 3;
  char* b0 = lds;
  char* b1 = lds + 65536;
  stage_half(At, lda, b0, 0, 0, tid);
  stage_half(At, lda, b0, 1, 0, tid);
  stage_half(Bt, ldb, b0 + 32768, 0, 0, tid);
  stage_half(Bt, ldb, b0 + 32768, 1, 0, tid);
  stage_half(At, lda, b1, 0, 64, tid);
  constexpr int ITERS = NT / 2;
  f16x8 bf[4];
#pragma unroll 1
  for (int it = 0; it < ITERS; ++it) {
    const int kt = 2 * it;
    const bool stg = (it < ITERS - 1);
    vmwait<2>(); blockbar();
    // ---- G1: ph0, ph1, ph2 (barrier-free; writes b1, reads b0) ----
    stage_half(At, lda, b1, 1, (kt + 1) * 64, tid);
    PHASE(b0, 0, 0, true)
    stage_half(Bt, ldb, b1 + 32768, 0, (kt + 1) * 64, tid);
    PHASE(b0, 0, 1, false)
    stage_half(Bt, ldb, b1 + 32768, 1, (kt + 1) * 64, tid);
    PHASE(b0, 1, 0, true)
    blockbar();
    // ---- G2: ph3 ----
    if (stg) stage_half(At, lda, b0, 0, (kt + 2) * 64, tid);
    PHASE(b0, 1, 1, false)
    if (stg) { vmwait<2>(); } else { vmwait<0>(); }
    blockbar();
    // ---- G3: ph4, ph5, ph6 (barrier-free; writes b0, reads b1) ----
    if (stg) stage_half(At, lda, b0, 1, (kt + 2) * 64, tid);
    PHASE(b1, 0, 0, true)
    if (stg) stage_half(Bt, ldb, b0 + 32768, 0, (kt + 2) * 64, tid);
    PHASE(b1, 0, 1, false)
    if (stg) stage_half(Bt, ldb, b0 + 32768, 1, (kt + 2) * 64, tid);
    PHASE(b1, 1, 0, true)
    blockbar();
    // ---- G4: ph7 ----
    if (stg) stage_half(At, lda, b1, 0, (kt + 3) * 64, tid);
    PHASE(b1, 1, 1, false)
  }
}

// ---------------- fused prep (cvt + vals + transpose in one launch) ----------------
__global__ __launch_bounds__(256) void k_prep(
    const float* __restrict__ x, const float* __restrict__ h,
    const float* __restrict__ Wi, const float* __restrict__ Wh, const float* __restrict__ Wih,
    const float* __restrict__ vals, const int* __restrict__ mptr,
    __half* __restrict__ x_h, __half* __restrict__ h_h,
    __half* __restrict__ Wip_h, __half* __restrict__ Whp_h, __half* __restrict__ Wih_h,
    float* __restrict__ nv, __half* __restrict__ vals_h, float* __restrict__ rmn,
    __half* __restrict__ vT) {
  __shared__ float tile[32][33];
  const int bid = blockIdx.x;
  if (bid < 6400) {
    int gq = bid * 256 + threadIdx.x;
    const float* src; __half* dst; int si, di;
    if (gq < 524288) {
      src = x; dst = x_h; si = di = gq * 4;
    } else if (gq < 1048576) {
      src = h; dst = h_h; si = di = (gq - 524288) * 4;
    } else if (gq < 1310720) {
      int iq = gq - 1048576;
      int jp = iq >> 7, k4 = (iq & 127) << 2;
      int U = jp >> 6, g = (jp >> 4) & 3, r = jp & 15;
      int u = U * 16 + r;
      int orig = g * 512 + u + (g == 3 ? 3 : 0);
      src = Wi; dst = Wip_h; si = orig * 512 + k4; di = jp * 512 + k4;
    } else if (gq < 1572864) {
      int iq = gq - 1310720;
      int jp = iq >> 7, k4 = (iq & 127) << 2;
      int U = jp >> 6, g = (jp >> 4) & 3, r = jp & 15;
      int u = U * 16 + r;
      int orig = g * 512 + u + (g == 3 ? 3 : 0);
      src = Wh; dst = Whp_h; si = orig * 512 + k4; di = jp * 512 + k4;
    } else if (gq < 1638400) {
      int iq = gq - 1572864;
      src = Wih; dst = Wih_h; si = di = iq * 4;
    } else return;
    float4 v = *(const float4*)(src + si);
    *(__half2*)(dst + di)     = __floats2half2_rn(v.x, v.y);
    *(__half2*)(dst + di + 2) = __floats2half2_rn(v.z, v.w);
  } else if (bid < 8448) {
    const int row  = (bid - 6400) * 4 + (threadIdx.x >> 6);
    const int lane = threadIdx.x & 63;
    const float* vr = vals + (size_t)row * HH + lane * 8;
    float4 a = *(const float4*)(vr);
    float4 b = *(const float4*)(vr + 4);
    if (((row + DICT - mptr[0]) & (DICT - 1)) >= BATCH) {
      float* nvp = nv + (size_t)row * HH + lane * 8;
      *(float4*)(nvp)     = a;
      *(float4*)(nvp + 4) = b;
    }
    __half* vh = vals_h + (size_t)row * HH + lane * 8;
    *(__half2*)(vh)     = __floats2half2_rn(a.x, a.y);
    *(__half2*)(vh + 2) = __floats2half2_rn(a.z, a.w);
    *(__half2*)(vh + 4) = __floats2half2_rn(b.x, b.y);
    *(__half2*)(vh + 6) = __floats2half2_rn(b.z, b.w);
    float ss = a.x * a.x + a.y * a.y + a.z * a.z + a.w * a.w
             + b.x * b.x + b.y * b.y + b.z * b.z + b.w * b.w;
    ss = waveReduceSum(ss);
    if (lane == 0) rmn[row] = 1.f / fmaxf(sqrtf(ss), 1e-12f);
  } else {
    const int idx = bid - 8448;
    const int r0 = (idx & 255) * 32, c0 = (idx >> 8) * 32;
    const int tr = threadIdx.x >> 5, tc = threadIdx.x & 31;
#pragma unroll
    for (int p = 0; p < 4; ++p)
      tile[tr + p * 8][tc] = vals[(size_t)(r0 + tr + p * 8) * HH + c0 + tc];
    __syncthreads();
#pragma unroll
    for (int p = 0; p < 4; ++p)
      vT[(size_t)(c0 + tr + p * 8) * DICT + r0 + tc] = __float2half(tile[tc][tr + p * 8]);
  }
}

// ---------------- main kernels ----------------
__global__ __launch_bounds__(256) void k_preact(
    const __half* __restrict__ x_h, const __half* __restrict__ h_h,
    const __half* __restrict__ Wip, const __half* __restrict__ Whp,
    const float* __restrict__ bi, const float* __restrict__ bh,
    const float* __restrict__ c_prev,
    float* __restrict__ ct, float* __restrict__ ot, __half* __restrict__ ct_h) {
  __shared__ char smem[2 * (BM * BKT * 2 + 128 * BKT * 2)] __attribute__((aligned(16)));
  const int tid = threadIdx.x;
  const int m0 = blockIdx.y * 128, n0 = blockIdx.x * 128;
  f32x4 acc[4][4]; zero_acc4(acc);
  gemm_seg<128, 4>(x_h, HH, Wip, HH, m0, n0, HH, smem, tid, acc);
  gemm_seg<128, 4>(h_h, HH, Whp, HH, m0, n0, HH, smem, tid, acc);
  const int lane = tid & 63, wid = tid >> 6, wr = wid >> 1, wc = wid & 1;
  const int r = lane & 15;
  const int u = ((n0 >> 6) + wc) * 16 + r;
  float bsum[4];
#pragma unroll
  for (int g = 0; g < 4; ++g) {
    int orig = g * 512 + u + (g == 3 ? 3 : 0);
    bsum[g] = bi[orig] + bh[orig];
  }
#pragma unroll
  for (int fi = 0; fi < 4; ++fi)
#pragma unroll
    for (int q = 0; q < 4; ++q) {
      int m = m0 + wr * 64 + fi * 16 + (lane >> 4) * 4 + q;
      float f  = sigmoidf_(acc[fi][0][q] + bsum[0]);
      float o  = sigmoidf_(acc[fi][1][q] + bsum[1]);
      float ii = sigmoidf_(acc[fi][2][q] + bsum[2]);
      float cn = tanhf(acc[fi][3][q] + bsum[3]);
      size_t off = (size_t)m * HH + u;
      float cc = c_prev[off] * f + ii * cn;
      ct[off] = cc; ot[off] = o; ct_h[off] = __float2half(cc);
    }
}

__global__ __launch_bounds__(256) void k_scalars(
    const float* __restrict__ x, const float* __restrict__ h,
    const float* __restrict__ Wi, const float* __restrict__ Wh,
    const float* __restrict__ bi, const float* __restrict__ bh,
    const float* __restrict__ ct,
    float* __restrict__ inps, float* __restrict__ leak,
    float* __restrict__ comp, float* __restrict__ rqn) {
  const int b = blockIdx.x, wid = threadIdx.x >> 6, lane = threadIdx.x & 63;
  const int j = lane * 8;
  if (wid < 3) {
    const float* wi = Wi + (size_t)(1536 + wid) * HH + j;
    const float* wh = Wh + (size_t)(1536 + wid) * HH + j;
    const float* xr = x + (size_t)b * HH + j;
    const float* hr = h + (size_t)b * HH + j;
    float4 xa = *(const float4*)(xr), xb = *(const float4*)(xr + 4);
    float4 wa = *(const float4*)(wi), wb = *(const float4*)(wi + 4);
    float4 ha = *(const float4*)(hr), hb = *(const float4*)(hr + 4);
    float4 va = *(const float4*)(wh), vb = *(const float4*)(wh + 4);
    float s = xa.x * wa.x + xa.y * wa.y + xa.z * wa.z + xa.w * wa.w
            + xb.x * wb.x + xb.y * wb.y + xb.z * wb.z + xb.w * wb.w
            + ha.x * va.x + ha.y * va.y + ha.z * va.z + ha.w * va.w
            + hb.x * vb.x + hb.y * vb.y + hb.z * vb.z + hb.w * vb.w;
    s = waveReduceSum(s);
    if (lane == 0) {
      float v = sigmoidf_(s + bi[1536 + wid] + bh[1536 + wid]);
      if (wid == 0) inps[b] = v; else if (wid == 1) leak[b] = v; else comp[b] = v;
    }
  } else {
    const float* cr = ct + (size_t)b * HH + j;
    float4 a = *(const float4*)(cr), d = *(const float4*)(cr + 4);
    float ss = a.x * a.x + a.y * a.y + a.z * a.z + a.w * a.w
             + d.x * d.x + d.y * d.y + d.z * d.z + d.w * d.w;
    ss = waveReduceSum(ss);
    if (lane == 0) rqn[b] = 1.f / fmaxf(sqrtf(ss), 1e-12f);
  }
}

// sim GEMM: 256x256, 8-phase grouped-barrier, 128KB dynamic LDS.
__global__ __launch_bounds__(512, 1) void k_sim(
    const __half* __restrict__ ct_h, const __half* __restrict__ vals_h,
    const float* __restrict__ rqn, const float* __restrict__ rmn,
    __half* __restrict__ sim_h) {
  extern __shared__ char dsm[];
  const int tid = threadIdx.x, lane = tid & 63, wid = tid >> 6;
  const int wr = wid >> 2, wc = wid & 3;
  const int bid = blockIdx.x;
  const int xcd = bid & 7, idx = bid >> 3;
  const int nt_ = xcd * 4 + (idx & 3);
  const int mt_ = idx >> 2;
  const int m0 = mt_ * 256, n0 = nt_ * 256;
  f32x4 acc[8][4];
  { f32x4 z = {0.f, 0.f, 0.f, 0.f};
#pragma unroll
    for (int i = 0; i < 8; ++i)
#pragma unroll
      for (int j = 0; j < 4; ++j) acc[i][j] = z; }
  gemm_8ph<8>(ct_h + (size_t)m0 * HH, HH, vals_h + (size_t)n0 * HH, HH, dsm, tid, acc);
  float* T = (float*)dsm;
  const int g = lane >> 4, r = lane & 15;
  const int lrow = tid >> 3;
  const int seg  = (tid & 7) * 16;
  float rmv0[16], rmv1[16];
#pragma unroll
  for (int k = 0; k < 4; ++k) {
    *(float4*)(rmv0 + k * 4) = *(const float4*)(rmn + n0 + seg + k * 4);
    *(float4*)(rmv1 + k * 4) = *(const float4*)(rmn + n0 + 128 + seg + k * 4);
  }
  __syncthreads();
#pragma unroll
  for (int p = 0; p < 4; ++p) {
    if (p) __syncthreads();
#pragma unroll
    for (int hf = 0; hf < 2; ++hf)
#pragma unroll
      for (int j = 0; j < 4; ++j)
#pragma unroll
        for (int q = 0; q < 4; ++q)
          T[(hf * 32 + wr * 16 + g * 4 + q) * 132 + wc * 64 + j * 16 + r] =
              acc[p * 2 + hf][j][q];
    __syncthreads();
    int m = m0 + p * 64 + lrow;
    float rq = rqn[m];
    const float* Tr = T + lrow * 132;
    float v[16], w[16];
#pragma unroll
    for (int k = 0; k < 4; ++k) {
      *(float4*)(v + k * 4) = *(const float4*)(Tr + seg + k * 4);
      *(float4*)(w + k * 4) = *(const float4*)(Tr + 128 + seg + k * 4);
    }
    f16x8 o0, o1, o2, o3;
#pragma unroll
    for (int j = 0; j < 8; ++j) o0[j] = (_Float16)(v[j] * rq * rmv0[j]);
#pragma unroll
    for (int j = 0; j < 8; ++j) o1[j] = (_Float16)(v[8 + j] * rq * rmv0[8 + j]);
#pragma unroll
    for (int j = 0; j < 8; ++j) o2[j] = (_Float16)(w[j] * rq * rmv1[j]);
#pragma unroll
    for (int j = 0; j < 8; ++j) o3[j] = (_Float16)(w[8 + j] * rq * rmv1[8 + j]);
    *(f16x8*)(sim_h + (size_t)m * DICT + n0 + seg)           = o0;
    *(f16x8*)(sim_h + (size_t)m * DICT + n0 + seg + 8)       = o1;
    *(f16x8*)(sim_h + (size_t)m * DICT + n0 + 128 + seg)     = o2;
    *(f16x8*)(sim_h + (size_t)m * DICT + n0 + 128 + seg + 8) = o3;
  }
}

// LCA: thread owns 32 contiguous dict elems (f16 vector io)
__global__ __launch_bounds__(256) void k_lca(
    const __half* __restrict__ sim_h, const float* __restrict__ inps,
    const float* __restrict__ leak, const float* __restrict__ comp,
    __half* __restrict__ w_h) {
  const int b = blockIdx.x, t = threadIdx.x;
  const __half* srow = sim_h + (size_t)b * DICT + t * 32;
  const float ffs = DTT * inps[b];
  const float a   = 1.0f - DTT * leak[b] + DTT * comp[b];
  const float cdt = DTT * comp[b];
  float ff[32], V[32];
#pragma unroll
  for (int i = 0; i < 4; ++i) {
    f16x8 v8 = *(const f16x8*)(srow + i * 8);
#pragma unroll
    for (int j = 0; j < 8; ++j) { ff[i * 8 + j] = ffs * (float)v8[j]; V[i * 8 + j] = 0.f; }
  }
  __shared__ float ps[4];
  for (int it = 0; it < NCYC; ++it) {
    float s = 0.f;
#pragma unroll
    for (int i = 0; i < 32; ++i) s += V[i];
    s = waveReduceSum(s);
    if ((t & 63) == 0) ps[t >> 6] = s;
    __syncthreads();
    float S = ps[0] + ps[1] + ps[2] + ps[3];
    __syncthreads();
    float sub = cdt * S;
#pragma unroll
    for (int i = 0; i < 32; ++i) V[i] = fmaxf(fmaf(a, V[i], ff[i] - sub), 0.f);
  }
  __half* wrow = w_h + (size_t)b * DICT + t * 32;
#pragma unroll
  for (int i = 0; i < 4; ++i) {
    f16x8 o8;
#pragma unroll
    for (int j = 0; j < 8; ++j) o8[j] = (_Float16)V[i * 8 + j];
    *(f16x8*)(wrow + i * 8) = o8;
  }
}

// split-K mt GEMM (r5-proven): 128x64 tile, 2-phase counted vmcnt, split-K=4,
// grid 1024 XCD-bijective. Partial stored as f16.
__global__ __launch_bounds__(256) void k_mt_p(
    const __half* __restrict__ w_h, const __half* __restrict__ vT_h,
    __half* __restrict__ partial) {
  __shared__ char smem[2 * (BM * BKT * 2 + 64 * BKT * 2)] __attribute__((aligned(16)));
  const int tid = threadIdx.x, bid = blockIdx.x;
  const int xcd = bid & 7, idx = bid >> 3;
  const int n = idx & 7, q = idx >> 3;
  const int g = (q << 3) | xcd;     // g = m*4 + s
  const int m = g >> 2, s = g & 3;
  const int m0 = m * 128, n0 = n * 64;
  f32x4 acc[4][2]; zero_acc2(acc);
  gemm_seg<64, 2>(w_h + s * 2048, DICT, vT_h + s * 2048, DICT, m0, n0, 2048, smem, tid, acc);
  const int lane = tid & 63, wid = tid >> 6, wr = wid >> 1, wc = wid & 1;
  __half* pbase = partial + (size_t)s * (BATCH * HH);
  float* T = (float*)smem;
  const int gg = lane >> 4, r = lane & 15;
  const int lrow = tid >> 3, c8 = (tid & 7) * 8;
#pragma unroll
  for (int fi = 0; fi < 4; ++fi) {
    if (fi) __syncthreads();
#pragma unroll
    for (int fj = 0; fj < 2; ++fj)
#pragma unroll
      for (int qq = 0; qq < 4; ++qq)
        T[(wr * 16 + gg * 4 + qq) * 68 + wc * 32 + fj * 16 + r] = acc[fi][fj][qq];
    __syncthreads();
    int mm = m0 + (lrow >> 4) * 64 + fi * 16 + (lrow & 15);
    float4 v0 = *(const float4*)(T + lrow * 68 + c8);
    float4 v1 = *(const float4*)(T + lrow * 68 + c8 + 4);
    f16x8 o8;
    o8[0] = (_Float16)v0.x; o8[1] = (_Float16)v0.y;
    o8[2] = (_Float16)v0.z; o8[3] = (_Float16)v0.w;
    o8[4] = (_Float16)v1.x; o8[5] = (_Float16)v1.y;
    o8[6] = (_Float16)v1.z; o8[7] = (_Float16)v1.w;
    *(f16x8*)(pbase + (size_t)mm * HH + n0 + c8) = o8;
  }
}

// reduce 4 f16 partials + full epilogue (cm, ht, nv scatter, ht_h)
__global__ __launch_bounds__(256) void k_mt_red(
    const __half* __restrict__ partial,
    const float* __restrict__ ct, const float* __restrict__ ot, const int* __restrict__ mptr,
    float* __restrict__ out_mt, float* __restrict__ out_cmt, float* __restrict__ out_ht,
    float* __restrict__ out_nv, __half* __restrict__ ht_h) {
  const int i4 = blockIdx.x * 256 + threadIdx.x;
  const size_t off = (size_t)i4 * 4;
  const int m = i4 >> 7;
  float4 p = make_float4(0.f, 0.f, 0.f, 0.f);
#pragma unroll
  for (int s = 0; s < 4; ++s) {
    const __half* ps_ = partial + (size_t)s * 2097152 + off;
    float2 a = __half22float2(*(const __half2*)(ps_));
    float2 b = __half22float2(*(const __half2*)(ps_ + 2));
    p.x += a.x; p.y += a.y; p.z += b.x; p.w += b.y;
  }
  float4 c4 = *(const float4*)(ct + off);
  float4 o4 = *(const float4*)(ot + off);
  float4 cm, hv;
  cm.x = c4.x + p.x; hv.x = o4.x * tanhf(cm.x);
  cm.y = c4.y + p.y; hv.y = o4.y * tanhf(cm.y);
  cm.z = c4.z + p.z; hv.z = o4.z * tanhf(cm.z);
  cm.w = c4.w + p.w; hv.w = o4.w * tanhf(cm.w);
  *(float4*)(out_mt + off)  = p;
  *(float4*)(out_cmt + off) = cm;
  *(float4*)(out_ht + off)  = hv;
  *(__half2*)(ht_h + off)     = __floats2half2_rn(hv.x, hv.y);
  *(__half2*)(ht_h + off + 2) = __floats2half2_rn(hv.z, hv.w);
  const int nvrow = (mptr[0] + m) & (DICT - 1);
  *(float4*)(out_nv + (size_t)nvrow * HH + (off & 511)) = cm;
}

__global__ __launch_bounds__(256) void k_a2c(
    const __half* __restrict__ ht_h, const __half* __restrict__ Wih_h,
    const float* __restrict__ bih, float* __restrict__ a2c) {
  __shared__ char smem[2 * (BM * BKT * 2 + 64 * BKT * 2)] __attribute__((aligned(16)));
  const int tid = threadIdx.x;
  const int bid = blockIdx.x;
  const int xn = (bid >> 3) & 7, ym = (bid & 7) | ((bid >> 6) << 3);
  const int m0 = ym * 128, n0 = xn * 64;
  f32x4 acc[4][2]; zero_acc2(acc);
  gemm_seg<64, 2>(ht_h, HH, Wih_h, HH, m0, n0, HH, smem, tid, acc);
  const int lane = tid & 63, wid = tid >> 6, wr = wid >> 1, wc = wid & 1;
  float* T = (float*)smem;
  const int gg = lane >> 4, r = lane & 15;
  const int lrow = tid >> 3, c8 = (tid & 7) * 8;
  float4 b0 = *(const float4*)(bih + n0 + c8);
  float4 b1 = *(const float4*)(bih + n0 + c8 + 4);
#pragma unroll
  for (int fi = 0; fi < 4; ++fi) {
    if (fi) __syncthreads();
#pragma unroll
    for (int fj = 0; fj < 2; ++fj)
#pragma unroll
      for (int qq = 0; qq < 4; ++qq)
        T[(wr * 16 + gg * 4 + qq) * 68 + wc * 32 + fj * 16 + r] = acc[fi][fj][qq];
    __syncthreads();
    int mm = m0 + (lrow >> 4) * 64 + fi * 16 + (lrow & 15);
    float4 v0 = *(const float4*)(T + lrow * 68 + c8);
    float4 v1 = *(const float4*)(T + lrow * 68 + c8 + 4);
    v0.x = fmaxf(v0.x + b0.x, 0.f); v0.y = fmaxf(v0.y + b0.y, 0.f);
    v0.z = fmaxf(v0.z + b0.z, 0.f); v0.w = fmaxf(v0.w + b0.w, 0.f);
    v1.x = fmaxf(v1.x + b1.x, 0.f); v1.y = fmaxf(v1.y + b1.y, 0.f);
    v1.z = fmaxf(v1.z + b1.z, 0.f); v1.w = fmaxf(v1.w + b1.w, 0.f);
    float* dst = a2c + (size_t)mm * HH + n0 + c8;
    *(float4*)dst       = v0;
    *(float4*)(dst + 4) = v1;
  }
}

__global__ __launch_bounds__(256) void k_actor(
    const float* __restrict__ a2c,
    const float* __restrict__ Wact, const float* __restrict__ bact,
    const float* __restrict__ Wcr, const float* __restrict__ bcr,
    float* __restrict__ out_pi, float* __restrict__ out_val) {
  const int b = blockIdx.x * 4 + (threadIdx.x >> 6);
  const int lane = threadIdx.x & 63;
  const float* hrow = a2c + (size_t)b * HH;
  float4 a0 = *(const float4*)(hrow + (lane << 3));
  float4 a1 = *(const float4*)(hrow + (lane << 3) + 4);
  float lg[17];
#pragma unroll
  for (int o = 0; o < 17; ++o) {
    const float* wr = (o < 16) ? (Wact + (size_t)o * HH) : Wcr;
    float4 w0 = *(const float4*)(wr + (lane << 3));
    float4 w1 = *(const float4*)(wr + (lane << 3) + 4);
    float s = a0.x * w0.x + a0.y * w0.y + a0.z * w0.z + a0.w * w0.w
            + a1.x * w1.x + a1.y * w1.y + a1.z * w1.z + a1.w * w1.w;
    lg[o] = waveReduceSum(s);
  }
#pragma unroll
  for (int o = 0; o < 16; ++o) lg[o] += bact[o];
  float mx = lg[0];
#pragma unroll
  for (int o = 1; o < 16; ++o) mx = fmaxf(mx, lg[o]);
  float e[16], sum = 0.f;
#pragma unroll
  for (int o = 0; o < 16; ++o) { e[o] = __expf(lg[o] - mx); sum += e[o]; }
  float rs = 1.f / sum;
  if (lane == 0) {
#pragma unroll
    for (int o = 0; o < 16; ++o) out_pi[(size_t)b * 16 + o] = e[o] * rs;
    out_val[b] = lg[16] + bcr[0];
  }
}

// ---------------- launch ----------------
extern "C" void kernel_launch(void* const* d_in, const int* in_sizes, int n_in,
                              void* d_out, int out_size, void* d_ws, size_t ws_size,
                              hipStream_t stream) {
  const float* x    = (const float*)d_in[0];
  const float* h    = (const float*)d_in[1];
  const float* c    = (const float*)d_in[2];
  const float* Wi   = (const float*)d_in[3];
  const float* bi   = (const float*)d_in[4];
  const float* Wh   = (const float*)d_in[5];
  const float* bh   = (const float*)d_in[6];
  const float* vals = (const float*)d_in[7];
  const float* Wih  = (const float*)d_in[8];
  const float* bih  = (const float*)d_in[9];
  const float* Wact = (const float*)d_in[10];
  const float* bact = (const float*)d_in[11];
  const float* Wcr  = (const float*)d_in[12];
  const float* bcr  = (const float*)d_in[13];
  const int*   mptr = (const int*)d_in[14];

  float* F = (float*)d_ws;
  __half* w_h    = (__half*)F;
  __half* sim_h   = (__half*)(F + 16777216);
  float*  a2c     = F + 16777216;
  __half* partial = (__half*)(F + 33554432);  // 8.4M halves (4 x 4096 x 512)
  float*  ct     = F + 50331648;
  float*  ot     = F + 52428800;
  __half* ct_h   = (__half*)(F + 54525952);
  __half* vals_h = (__half*)(F + 55574528);
  __half* vT_h   = (__half*)(F + 57671680);
  __half* x_h    = (__half*)(F + 59768832);
  __half* ht_h   = x_h;
  __half* h_h    = (__half*)(F + 60817408);
  __half* Wip_h  = (__half*)(F + 61865984);
  __half* Whp_h  = (__half*)(F + 62423040);
  __half* Wih_h  = (__half*)(F + 62980096);
  float*  inps   = F + 63111168;
  float*  leak   = inps + 4096;
  float*  comp   = leak + 4096;
  float*  rqn    = comp + 4096;
  float*  rmn    = rqn + 4096;

  float* out     = (float*)d_out;
  float* out_pi  = out;
  float* out_val = out + 65536;
  float* out_ht  = out + 69632;
  float* out_cmt = out_ht + 2097152;
  float* out_mt  = out_cmt + 2097152;
  float* out_nv  = out_mt + 2097152;

  (void)hipFuncSetAttribute(reinterpret_cast<const void*>(k_sim),
                            hipFuncAttributeMaxDynamicSharedMemorySize, 131072);

  dim3 b256(256);
  dim3 b512(512);
  k_prep   <<<12544, b256, 0, stream>>>(x, h, Wi, Wh, Wih, vals, mptr,
                                        x_h, h_h, Wip_h, Whp_h, Wih_h,
                                        out_nv, vals_h, rmn, vT_h);
  k_preact <<<dim3(16, 32), b256, 0, stream>>>(x_h, h_h, Wip_h, Whp_h, bi, bh, c,
                                               ct, ot, ct_h);
  k_scalars<<<BATCH, b256, 0, stream>>>(x, h, Wi, Wh, bi, bh, ct, inps, leak, comp, rqn);
  k_sim    <<<512, b512, 131072, stream>>>(ct_h, vals_h, rqn, rmn, sim_h);
  k_lca    <<<BATCH, b256, 0, stream>>>(sim_h, inps, leak, comp, w_h);
  k_mt_p   <<<1024, b256, 0, stream>>>(w_h, vT_h, partial);
  k_mt_red <<<2048, b256, 0, stream>>>(partial, ct, ot, mptr,
                                       out_mt, out_cmt, out_ht, out_nv, ht_h);
  k_a2c    <<<256, b256, 0, stream>>>(ht_h, Wih_h, bih, a2c);
  k_actor  <<<BATCH / 4, b256, 0, stream>>>(a2c, Wact, bact, Wcr, bcr, out_pi, out_val);
}

// Round 16
// 217.224 us; speedup vs baseline: 1.0158x; 1.0158x over previous
//
#include <hip/hip_runtime.h>
#include <hip/hip_fp16.h>
#include <math.h>

#define HH    512
#define DICT  8192
#define BATCH 4096
#define NCYC  10
#define DTT   0.6f

#define BM  128
#define BKT 64

using f16x8 = __attribute__((ext_vector_type(8))) _Float16;
using f32x4 = __attribute__((ext_vector_type(4))) float;

__device__ __forceinline__ float sigmoidf_(float x) { return 1.0f / (1.0f + __expf(-x)); }

__device__ __forceinline__ float waveReduceSum(float v) {
#pragma unroll
  for (int o = 1; o < 64; o <<= 1) v += __shfl_xor(v, o);
  return v;
}

__device__ __forceinline__ void gld16(const void* g, void* l) {
  __builtin_amdgcn_global_load_lds(
      (const __attribute__((address_space(1))) void*)g,
      (__attribute__((address_space(3))) void*)l, 16, 0, 0);
}

template<int N> __device__ __forceinline__ void vmwait() {
  if constexpr (N == 8)      asm volatile("s_waitcnt vmcnt(8)" ::: "memory");
  else if constexpr (N == 6) asm volatile("s_waitcnt vmcnt(6)" ::: "memory");
  else if constexpr (N == 2) asm volatile("s_waitcnt vmcnt(2)" ::: "memory");
  else                       asm volatile("s_waitcnt vmcnt(0)" ::: "memory");
  __builtin_amdgcn_sched_barrier(0);
}

__device__ __forceinline__ void blockbar() {
  asm volatile("" ::: "memory");
  __builtin_amdgcn_s_barrier();
  __builtin_amdgcn_sched_barrier(0);
}

// ======== BKT=64 machinery (256-thread kernels: preact, a2c, mt_p) ========
template<int ROWS>
__device__ __forceinline__ void stage_tile(const __half* gbase, int ld, char* lds, int tid) {
  constexpr int ISS = ROWS * 8 / 256;
#pragma unroll
  for (int i = 0; i < ISS; ++i) {
    int cidx = i * 256 + tid;
    int row  = cidx >> 3;
    int slot = cidx & 7;
    int k4   = slot ^ (row & 7);
    gld16(gbase + (size_t)row * ld + k4 * 8, lds + cidx * 16);
  }
}

__device__ __forceinline__ f16x8 frag_ld(const char* lds, int row, int kchunk) {
  int slot = kchunk ^ (row & 7);
  return *(const f16x8*)(lds + row * 128 + slot * 16);
}

template<int FN>
__device__ __forceinline__ void tile_mfma(const char* As, const char* Bs,
                                          int lane, int wr, int wc, f32x4 (&acc)[4][FN]) {
  const int g = lane >> 4, r = lane & 15;
#pragma unroll
  for (int ks = 0; ks < 2; ++ks) {
    f16x8 af[4], bfr[FN];
#pragma unroll
    for (int i = 0; i < 4; ++i)
      af[i] = frag_ld(As, wr * 64 + i * 16 + r, ks * 4 + g);
#pragma unroll
    for (int j = 0; j < FN; ++j)
      bfr[j] = frag_ld(Bs, wc * (FN * 16) + j * 16 + r, ks * 4 + g);
#pragma unroll
    for (int i = 0; i < 4; ++i)
#pragma unroll
      for (int j = 0; j < FN; ++j)
        acc[i][j] = __builtin_amdgcn_mfma_f32_16x16x32_f16(af[i], bfr[j], acc[i][j], 0, 0, 0);
  }
}

template<int BN, int FN>
__device__ __forceinline__ void gemm_seg(const __half* A, int lda, const __half* B, int ldb,
                                         int m0, int n0, int K, char* lds, int tid,
                                         f32x4 (&acc)[4][FN]) {
  constexpr int ABYTES = BM * BKT * 2;
  constexpr int BBYTES = BN * BKT * 2;
  constexpr int BUF = ABYTES + BBYTES;
  constexpr int NL = (BM + BN) * 8 / 256;
  const int lane = tid & 63, wid = tid >> 6;
  const int wr = wid >> 1, wc = wid & 1;
  const int nt = K / BKT;
  const __half* Ab = A + (size_t)m0 * lda;
  const __half* Bb = B + (size_t)n0 * ldb;
  stage_tile<BM>(Ab, lda, lds, tid);
  stage_tile<BN>(Bb, ldb, lds + ABYTES, tid);
  int cur = 0;
  for (int t = 0; t < nt; ++t) {
    char* curb = lds + cur * BUF;
    if (t + 1 < nt) {
      char* nxt = lds + (cur ^ 1) * BUF;
      stage_tile<BM>(Ab + (t + 1) * BKT, lda, nxt, tid);
      stage_tile<BN>(Bb + (t + 1) * BKT, ldb, nxt + ABYTES, tid);
      vmwait<NL>();
    } else {
      vmwait<0>();
    }
    blockbar();
    tile_mfma<FN>(curb, curb + ABYTES, lane, wr, wc, acc);
    blockbar();
    cur ^= 1;
  }
}

__device__ __forceinline__ void zero_acc4(f32x4 (&a)[4][4]) {
  f32x4 z = {0.f, 0.f, 0.f, 0.f};
#pragma unroll
  for (int i = 0; i < 4; ++i)
#pragma unroll
    for (int j = 0; j < 4; ++j) a[i][j] = z;
}
__device__ __forceinline__ void zero_acc2(f32x4 (&a)[4][2]) {
  f32x4 z = {0.f, 0.f, 0.f, 0.f};
#pragma unroll
  for (int i = 0; i < 4; ++i)
#pragma unroll
    for (int j = 0; j < 2; ++j) a[i][j] = z;
}

// ======== 8-phase 256x256 machinery (512-thread kernel: sim) ========
__device__ __forceinline__ void stage_half(const __half* tilebase, int ld, char* ldstile,
                                           int h, int kcol, int tid) {
#pragma unroll
  for (int i = 0; i < 2; ++i) {
    int cidx = i * 512 + tid;
    int lrow = cidx >> 3;
    int slot = cidx & 7;
    int row  = h * 128 + lrow;
    int k4   = slot ^ (row & 7);
    gld16(tilebase + (size_t)row * ld + kcol + k4 * 8,
          ldstile + row * 128 + slot * 16);
  }
}

__device__ __forceinline__ f16x8 fragA8(const char* At, int fi, int wr, int ks, int lane) {
  int r = lane & 15, g = lane >> 4;
  int row = fi * 32 + wr * 16 + r;
  int slot = (ks * 4 + g) ^ (row & 7);
  return *(const f16x8*)(At + row * 128 + slot * 16);
}
__device__ __forceinline__ f16x8 fragB8(const char* Bt, int j, int wc, int ks, int lane) {
  int r = lane & 15, g = lane >> 4;
  int row = wc * 64 + j * 16 + r;
  int slot = (ks * 4 + g) ^ (row & 7);
  return *(const f16x8*)(Bt + row * 128 + slot * 16);
}

#define PHASE(TT, KS, MH, RB)                                                  \
  {                                                                            \
    if (RB) {                                                                  \
      _Pragma("unroll")                                                        \
      for (int j = 0; j < 4; ++j) bf[j] = fragB8((TT) + 32768, j, wc, KS, lane); \
    }                                                                          \
    f16x8 af[4];                                                               \
    _Pragma("unroll")                                                          \
    for (int i = 0; i < 4; ++i) af[i] = fragA8((TT), (MH)*4 + i, wr, KS, lane); \
    __builtin_amdgcn_s_setprio(1);                                             \
    _Pragma("unroll")                                                          \
    for (int i = 0; i < 4; ++i)                                                \
      _Pragma("unroll")                                                        \
      for (int j = 0; j < 4; ++j)                                              \
        acc[(MH)*4 + i][j] = __builtin_amdgcn_mfma_f32_16x16x32_f16(           \
            af[i], bf[j], acc[(MH)*4 + i][j], 0, 0, 0);                        \
    __builtin_amdgcn_s_setprio(0);                                             \
  }

template<int NT>
__device__ __forceinline__ void gemm_8ph(const __half* At, int lda,
                                         const __half* Bt, int ldb,
                                         char* lds, int tid, f32x4 (&acc)[8][4]) {
  const int lane = tid & 63, wid = tid >> 6;
  const int wr = wid >> 2, wc = wid & 3;
  char* b0 = lds;
  char* b1 = lds + 65536;
  stage_half(At, lda, b0, 0, 0, tid);
  stage_half(At, lda, b0, 1, 0, tid);
  stage_half(Bt, ldb, b0 + 32768, 0, 0, tid);
  stage_half(Bt, ldb, b0 + 32768, 1, 0, tid);
  stage_half(At, lda, b1, 0, 64, tid);
  constexpr int ITERS = NT / 2;
  f16x8 bf[4];
#pragma unroll 1
  for (int it = 0; it < ITERS; ++it) {
    const int kt = 2 * it;
    const bool stg = (it < ITERS - 1);
    vmwait<2>(); blockbar();
    stage_half(At, lda, b1, 1, (kt + 1) * 64, tid);
    PHASE(b0, 0, 0, true)
    blockbar();
    stage_half(Bt, ldb, b1 + 32768, 0, (kt + 1) * 64, tid);
    PHASE(b0, 0, 1, false)
    blockbar();
    stage_half(Bt, ldb, b1 + 32768, 1, (kt + 1) * 64, tid);
    PHASE(b0, 1, 0, true)
    blockbar();
    if (stg) stage_half(At, lda, b0, 0, (kt + 2) * 64, tid);
    PHASE(b0, 1, 1, false)
    if (stg) { vmwait<2>(); } else { vmwait<0>(); }
    blockbar();
    if (stg) stage_half(At, lda, b0, 1, (kt + 2) * 64, tid);
    PHASE(b1, 0, 0, true)
    blockbar();
    if (stg) stage_half(Bt, ldb, b0 + 32768, 0, (kt + 2) * 64, tid);
    PHASE(b1, 0, 1, false)
    blockbar();
    if (stg) stage_half(Bt, ldb, b0 + 32768, 1, (kt + 2) * 64, tid);
    PHASE(b1, 1, 0, true)
    blockbar();
    if (stg) stage_half(At, lda, b1, 0, (kt + 3) * 64, tid);
    PHASE(b1, 1, 1, false)
  }
}

// ---------------- fused prep (cvt + vals + transpose in one launch) ----------------
__global__ __launch_bounds__(256) void k_prep(
    const float* __restrict__ x, const float* __restrict__ h,
    const float* __restrict__ Wi, const float* __restrict__ Wh, const float* __restrict__ Wih,
    const float* __restrict__ vals, const int* __restrict__ mptr,
    __half* __restrict__ x_h, __half* __restrict__ h_h,
    __half* __restrict__ Wip_h, __half* __restrict__ Whp_h, __half* __restrict__ Wih_h,
    float* __restrict__ nv, __half* __restrict__ vals_h, float* __restrict__ rmn,
    __half* __restrict__ vT) {
  __shared__ float tile[32][33];
  const int bid = blockIdx.x;
  if (bid < 6400) {
    int gq = bid * 256 + threadIdx.x;
    const float* src; __half* dst; int si, di;
    if (gq < 524288) {
      src = x; dst = x_h; si = di = gq * 4;
    } else if (gq < 1048576) {
      src = h; dst = h_h; si = di = (gq - 524288) * 4;
    } else if (gq < 1310720) {
      int iq = gq - 1048576;
      int jp = iq >> 7, k4 = (iq & 127) << 2;
      int U = jp >> 6, g = (jp >> 4) & 3, r = jp & 15;
      int u = U * 16 + r;
      int orig = g * 512 + u + (g == 3 ? 3 : 0);
      src = Wi; dst = Wip_h; si = orig * 512 + k4; di = jp * 512 + k4;
    } else if (gq < 1572864) {
      int iq = gq - 1310720;
      int jp = iq >> 7, k4 = (iq & 127) << 2;
      int U = jp >> 6, g = (jp >> 4) & 3, r = jp & 15;
      int u = U * 16 + r;
      int orig = g * 512 + u + (g == 3 ? 3 : 0);
      src = Wh; dst = Whp_h; si = orig * 512 + k4; di = jp * 512 + k4;
    } else if (gq < 1638400) {
      int iq = gq - 1572864;
      src = Wih; dst = Wih_h; si = di = iq * 4;
    } else return;
    float4 v = *(const float4*)(src + si);
    *(__half2*)(dst + di)     = __floats2half2_rn(v.x, v.y);
    *(__half2*)(dst + di + 2) = __floats2half2_rn(v.z, v.w);
  } else if (bid < 8448) {
    const int row  = (bid - 6400) * 4 + (threadIdx.x >> 6);
    const int lane = threadIdx.x & 63;
    const float* vr = vals + (size_t)row * HH + lane * 8;
    float4 a = *(const float4*)(vr);
    float4 b = *(const float4*)(vr + 4);
    if (((row + DICT - mptr[0]) & (DICT - 1)) >= BATCH) {
      float* nvp = nv + (size_t)row * HH + lane * 8;
      *(float4*)(nvp)     = a;
      *(float4*)(nvp + 4) = b;
    }
    __half* vh = vals_h + (size_t)row * HH + lane * 8;
    *(__half2*)(vh)     = __floats2half2_rn(a.x, a.y);
    *(__half2*)(vh + 2) = __floats2half2_rn(a.z, a.w);
    *(__half2*)(vh + 4) = __floats2half2_rn(b.x, b.y);
    *(__half2*)(vh + 6) = __floats2half2_rn(b.z, b.w);
    float ss = a.x * a.x + a.y * a.y + a.z * a.z + a.w * a.w
             + b.x * b.x + b.y * b.y + b.z * b.z + b.w * b.w;
    ss = waveReduceSum(ss);
    if (lane == 0) rmn[row] = 1.f / fmaxf(sqrtf(ss), 1e-12f);
  } else {
    const int idx = bid - 8448;
    const int r0 = (idx & 255) * 32, c0 = (idx >> 8) * 32;
    const int tr = threadIdx.x >> 5, tc = threadIdx.x & 31;
#pragma unroll
    for (int p = 0; p < 4; ++p)
      tile[tr + p * 8][tc] = vals[(size_t)(r0 + tr + p * 8) * HH + c0 + tc];
    __syncthreads();
#pragma unroll
    for (int p = 0; p < 4; ++p)
      vT[(size_t)(c0 + tr + p * 8) * DICT + r0 + tc] = __float2half(tile[tc][tr + p * 8]);
  }
}

// ---------------- main kernels ----------------
__global__ __launch_bounds__(256) void k_preact(
    const __half* __restrict__ x_h, const __half* __restrict__ h_h,
    const __half* __restrict__ Wip, const __half* __restrict__ Whp,
    const float* __restrict__ bi, const float* __restrict__ bh,
    const float* __restrict__ c_prev,
    float* __restrict__ ct, float* __restrict__ ot, __half* __restrict__ ct_h) {
  __shared__ char smem[2 * (BM * BKT * 2 + 128 * BKT * 2)] __attribute__((aligned(16)));
  const int tid = threadIdx.x;
  const int m0 = blockIdx.y * 128, n0 = blockIdx.x * 128;
  f32x4 acc[4][4]; zero_acc4(acc);
  gemm_seg<128, 4>(x_h, HH, Wip, HH, m0, n0, HH, smem, tid, acc);
  gemm_seg<128, 4>(h_h, HH, Whp, HH, m0, n0, HH, smem, tid, acc);
  const int lane = tid & 63, wid = tid >> 6, wr = wid >> 1, wc = wid & 1;
  const int r = lane & 15;
  const int u = ((n0 >> 6) + wc) * 16 + r;
  float bsum[4];
#pragma unroll
  for (int g = 0; g < 4; ++g) {
    int orig = g * 512 + u + (g == 3 ? 3 : 0);
    bsum[g] = bi[orig] + bh[orig];
  }
#pragma unroll
  for (int fi = 0; fi < 4; ++fi)
#pragma unroll
    for (int q = 0; q < 4; ++q) {
      int m = m0 + wr * 64 + fi * 16 + (lane >> 4) * 4 + q;
      float f  = sigmoidf_(acc[fi][0][q] + bsum[0]);
      float o  = sigmoidf_(acc[fi][1][q] + bsum[1]);
      float ii = sigmoidf_(acc[fi][2][q] + bsum[2]);
      float cn = tanhf(acc[fi][3][q] + bsum[3]);
      size_t off = (size_t)m * HH + u;
      float cc = c_prev[off] * f + ii * cn;
      ct[off] = cc; ot[off] = o; ct_h[off] = __float2half(cc);
    }
}

__global__ __launch_bounds__(256) void k_scalars(
    const float* __restrict__ x, const float* __restrict__ h,
    const float* __restrict__ Wi, const float* __restrict__ Wh,
    const float* __restrict__ bi, const float* __restrict__ bh,
    const float* __restrict__ ct,
    float* __restrict__ inps, float* __restrict__ leak,
    float* __restrict__ comp, float* __restrict__ rqn) {
  const int b = blockIdx.x, wid = threadIdx.x >> 6, lane = threadIdx.x & 63;
  const int j = lane * 8;
  if (wid < 3) {
    const float* wi = Wi + (size_t)(1536 + wid) * HH + j;
    const float* wh = Wh + (size_t)(1536 + wid) * HH + j;
    const float* xr = x + (size_t)b * HH + j;
    const float* hr = h + (size_t)b * HH + j;
    float4 xa = *(const float4*)(xr), xb = *(const float4*)(xr + 4);
    float4 wa = *(const float4*)(wi), wb = *(const float4*)(wi + 4);
    float4 ha = *(const float4*)(hr), hb = *(const float4*)(hr + 4);
    float4 va = *(const float4*)(wh), vb = *(const float4*)(wh + 4);
    float s = xa.x * wa.x + xa.y * wa.y + xa.z * wa.z + xa.w * wa.w
            + xb.x * wb.x + xb.y * wb.y + xb.z * wb.z + xb.w * wb.w
            + ha.x * va.x + ha.y * va.y + ha.z * va.z + ha.w * va.w
            + hb.x * vb.x + hb.y * vb.y + hb.z * vb.z + hb.w * vb.w;
    s = waveReduceSum(s);
    if (lane == 0) {
      float v = sigmoidf_(s + bi[1536 + wid] + bh[1536 + wid]);
      if (wid == 0) inps[b] = v; else if (wid == 1) leak[b] = v; else comp[b] = v;
    }
  } else {
    const float* cr = ct + (size_t)b * HH + j;
    float4 a = *(const float4*)(cr), d = *(const float4*)(cr + 4);
    float ss = a.x * a.x + a.y * a.y + a.z * a.z + a.w * a.w
             + d.x * d.x + d.y * d.y + d.z * d.z + d.w * d.w;
    ss = waveReduceSum(ss);
    if (lane == 0) rqn[b] = 1.f / fmaxf(sqrtf(ss), 1e-12f);
  }
}

// sim GEMM: 256x256, 8-phase, 128KB dynamic LDS, conflict-free float4 epilogue.
__global__ __launch_bounds__(512, 1) void k_sim(
    const __half* __restrict__ ct_h, const __half* __restrict__ vals_h,
    const float* __restrict__ rqn, const float* __restrict__ rmn,
    __half* __restrict__ sim_h) {
  extern __shared__ char dsm[];
  const int tid = threadIdx.x, lane = tid & 63, wid = tid >> 6;
  const int wr = wid >> 2, wc = wid & 3;
  const int bid = blockIdx.x;
  const int xcd = bid & 7, idx = bid >> 3;
  const int nt_ = xcd * 4 + (idx & 3);
  const int mt_ = idx >> 2;
  const int m0 = mt_ * 256, n0 = nt_ * 256;
  f32x4 acc[8][4];
  { f32x4 z = {0.f, 0.f, 0.f, 0.f};
#pragma unroll
    for (int i = 0; i < 8; ++i)
#pragma unroll
      for (int j = 0; j < 4; ++j) acc[i][j] = z; }
  gemm_8ph<8>(ct_h + (size_t)m0 * HH, HH, vals_h + (size_t)n0 * HH, HH, dsm, tid, acc);
  float* T = (float*)dsm;
  const int g = lane >> 4, r = lane & 15;
  const int lrow = tid >> 3;
  const int seg  = (tid & 7) * 16;
  float rmv0[16], rmv1[16];
#pragma unroll
  for (int k = 0; k < 4; ++k) {
    *(float4*)(rmv0 + k * 4) = *(const float4*)(rmn + n0 + seg + k * 4);
    *(float4*)(rmv1 + k * 4) = *(const float4*)(rmn + n0 + 128 + seg + k * 4);
  }
  __syncthreads();
#pragma unroll
  for (int p = 0; p < 4; ++p) {
    if (p) __syncthreads();
#pragma unroll
    for (int hf = 0; hf < 2; ++hf)
#pragma unroll
      for (int j = 0; j < 4; ++j)
#pragma unroll
        for (int q = 0; q < 4; ++q)
          T[(hf * 32 + wr * 16 + g * 4 + q) * 132 + wc * 64 + j * 16 + r] =
              acc[p * 2 + hf][j][q];
    __syncthreads();
    int m = m0 + p * 64 + lrow;
    float rq = rqn[m];
    const float* Tr = T + lrow * 132;
    float v[16], w[16];
#pragma unroll
    for (int k = 0; k < 4; ++k) {
      *(float4*)(v + k * 4) = *(const float4*)(Tr + seg + k * 4);
      *(float4*)(w + k * 4) = *(const float4*)(Tr + 128 + seg + k * 4);
    }
    f16x8 o0, o1, o2, o3;
#pragma unroll
    for (int j = 0; j < 8; ++j) o0[j] = (_Float16)(v[j] * rq * rmv0[j]);
#pragma unroll
    for (int j = 0; j < 8; ++j) o1[j] = (_Float16)(v[8 + j] * rq * rmv0[8 + j]);
#pragma unroll
    for (int j = 0; j < 8; ++j) o2[j] = (_Float16)(w[j] * rq * rmv1[j]);
#pragma unroll
    for (int j = 0; j < 8; ++j) o3[j] = (_Float16)(w[8 + j] * rq * rmv1[8 + j]);
    *(f16x8*)(sim_h + (size_t)m * DICT + n0 + seg)           = o0;
    *(f16x8*)(sim_h + (size_t)m * DICT + n0 + seg + 8)       = o1;
    *(f16x8*)(sim_h + (size_t)m * DICT + n0 + 128 + seg)     = o2;
    *(f16x8*)(sim_h + (size_t)m * DICT + n0 + 128 + seg + 8) = o3;
  }
}

// LCA: thread owns 32 contiguous dict elems (f16 vector io)
__global__ __launch_bounds__(256) void k_lca(
    const __half* __restrict__ sim_h, const float* __restrict__ inps,
    const float* __restrict__ leak, const float* __restrict__ comp,
    __half* __restrict__ w_h) {
  const int b = blockIdx.x, t = threadIdx.x;
  const __half* srow = sim_h + (size_t)b * DICT + t * 32;
  const float ffs = DTT * inps[b];
  const float a   = 1.0f - DTT * leak[b] + DTT * comp[b];
  const float cdt = DTT * comp[b];
  float ff[32], V[32];
#pragma unroll
  for (int i = 0; i < 4; ++i) {
    f16x8 v8 = *(const f16x8*)(srow + i * 8);
#pragma unroll
    for (int j = 0; j < 8; ++j) { ff[i * 8 + j] = ffs * (float)v8[j]; V[i * 8 + j] = 0.f; }
  }
  __shared__ float ps[4];
  for (int it = 0; it < NCYC; ++it) {
    float s = 0.f;
#pragma unroll
    for (int i = 0; i < 32; ++i) s += V[i];
    s = waveReduceSum(s);
    if ((t & 63) == 0) ps[t >> 6] = s;
    __syncthreads();
    float S = ps[0] + ps[1] + ps[2] + ps[3];
    __syncthreads();
    float sub = cdt * S;
#pragma unroll
    for (int i = 0; i < 32; ++i) V[i] = fmaxf(fmaf(a, V[i], ff[i] - sub), 0.f);
  }
  __half* wrow = w_h + (size_t)b * DICT + t * 32;
#pragma unroll
  for (int i = 0; i < 4; ++i) {
    f16x8 o8;
#pragma unroll
    for (int j = 0; j < 8; ++j) o8[j] = (_Float16)V[i * 8 + j];
    *(f16x8*)(wrow + i * 8) = o8;
  }
}

// split-K mt GEMM (r5-proven): 128x64 tile, 2-phase counted vmcnt, split-K=4,
// grid 1024 XCD-bijective. Partial stored as f16.
__global__ __launch_bounds__(256) void k_mt_p(
    const __half* __restrict__ w_h, const __half* __restrict__ vT_h,
    __half* __restrict__ partial) {
  __shared__ char smem[2 * (BM * BKT * 2 + 64 * BKT * 2)] __attribute__((aligned(16)));
  const int tid = threadIdx.x, bid = blockIdx.x;
  const int xcd = bid & 7, idx = bid >> 3;
  const int n = idx & 7, q = idx >> 3;
  const int g = (q << 3) | xcd;     // g = m*4 + s
  const int m = g >> 2, s = g & 3;
  const int m0 = m * 128, n0 = n * 64;
  f32x4 acc[4][2]; zero_acc2(acc);
  gemm_seg<64, 2>(w_h + s * 2048, DICT, vT_h + s * 2048, DICT, m0, n0, 2048, smem, tid, acc);
  const int lane = tid & 63, wid = tid >> 6, wr = wid >> 1, wc = wid & 1;
  __half* pbase = partial + (size_t)s * (BATCH * HH);
  float* T = (float*)smem;
  const int gg = lane >> 4, r = lane & 15;
  const int lrow = tid >> 3, c8 = (tid & 7) * 8;
#pragma unroll
  for (int fi = 0; fi < 4; ++fi) {
    if (fi) __syncthreads();
#pragma unroll
    for (int fj = 0; fj < 2; ++fj)
#pragma unroll
      for (int qq = 0; qq < 4; ++qq)
        T[(wr * 16 + gg * 4 + qq) * 68 + wc * 32 + fj * 16 + r] = acc[fi][fj][qq];
    __syncthreads();
    int mm = m0 + (lrow >> 4) * 64 + fi * 16 + (lrow & 15);
    float4 v0 = *(const float4*)(T + lrow * 68 + c8);
    float4 v1 = *(const float4*)(T + lrow * 68 + c8 + 4);
    f16x8 o8;
    o8[0] = (_Float16)v0.x; o8[1] = (_Float16)v0.y;
    o8[2] = (_Float16)v0.z; o8[3] = (_Float16)v0.w;
    o8[4] = (_Float16)v1.x; o8[5] = (_Float16)v1.y;
    o8[6] = (_Float16)v1.z; o8[7] = (_Float16)v1.w;
    *(f16x8*)(pbase + (size_t)mm * HH + n0 + c8) = o8;
  }
}

// reduce 4 f16 partials + full epilogue (cm, ht, nv scatter, ht_h)
__global__ __launch_bounds__(256) void k_mt_red(
    const __half* __restrict__ partial,
    const float* __restrict__ ct, const float* __restrict__ ot, const int* __restrict__ mptr,
    float* __restrict__ out_mt, float* __restrict__ out_cmt, float* __restrict__ out_ht,
    float* __restrict__ out_nv, __half* __restrict__ ht_h) {
  const int i4 = blockIdx.x * 256 + threadIdx.x;
  const size_t off = (size_t)i4 * 4;
  const int m = i4 >> 7;
  float4 p = make_float4(0.f, 0.f, 0.f, 0.f);
#pragma unroll
  for (int s = 0; s < 4; ++s) {
    const __half* ps_ = partial + (size_t)s * 2097152 + off;
    float2 a = __half22float2(*(const __half2*)(ps_));
    float2 b = __half22float2(*(const __half2*)(ps_ + 2));
    p.x += a.x; p.y += a.y; p.z += b.x; p.w += b.y;
  }
  float4 c4 = *(const float4*)(ct + off);
  float4 o4 = *(const float4*)(ot + off);
  float4 cm, hv;
  cm.x = c4.x + p.x; hv.x = o4.x * tanhf(cm.x);
  cm.y = c4.y + p.y; hv.y = o4.y * tanhf(cm.y);
  cm.z = c4.z + p.z; hv.z = o4.z * tanhf(cm.z);
  cm.w = c4.w + p.w; hv.w = o4.w * tanhf(cm.w);
  *(float4*)(out_mt + off)  = p;
  *(float4*)(out_cmt + off) = cm;
  *(float4*)(out_ht + off)  = hv;
  *(__half2*)(ht_h + off)     = __floats2half2_rn(hv.x, hv.y);
  *(__half2*)(ht_h + off + 2) = __floats2half2_rn(hv.z, hv.w);
  const int nvrow = (mptr[0] + m) & (DICT - 1);
  *(float4*)(out_nv + (size_t)nvrow * HH + (off & 511)) = cm;
}

__global__ __launch_bounds__(256) void k_a2c(
    const __half* __restrict__ ht_h, const __half* __restrict__ Wih_h,
    const float* __restrict__ bih, float* __restrict__ a2c) {
  __shared__ char smem[2 * (BM * BKT * 2 + 64 * BKT * 2)] __attribute__((aligned(16)));
  const int tid = threadIdx.x;
  const int bid = blockIdx.x;
  const int xn = (bid >> 3) & 7, ym = (bid & 7) | ((bid >> 6) << 3);
  const int m0 = ym * 128, n0 = xn * 64;
  f32x4 acc[4][2]; zero_acc2(acc);
  gemm_seg<64, 2>(ht_h, HH, Wih_h, HH, m0, n0, HH, smem, tid, acc);
  const int lane = tid & 63, wid = tid >> 6, wr = wid >> 1, wc = wid & 1;
  float* T = (float*)smem;
  const int gg = lane >> 4, r = lane & 15;
  const int lrow = tid >> 3, c8 = (tid & 7) * 8;
  float4 b0 = *(const float4*)(bih + n0 + c8);
  float4 b1 = *(const float4*)(bih + n0 + c8 + 4);
#pragma unroll
  for (int fi = 0; fi < 4; ++fi) {
    if (fi) __syncthreads();
#pragma unroll
    for (int fj = 0; fj < 2; ++fj)
#pragma unroll
      for (int qq = 0; qq < 4; ++qq)
        T[(wr * 16 + gg * 4 + qq) * 68 + wc * 32 + fj * 16 + r] = acc[fi][fj][qq];
    __syncthreads();
    int mm = m0 + (lrow >> 4) * 64 + fi * 16 + (lrow & 15);
    float4 v0 = *(const float4*)(T + lrow * 68 + c8);
    float4 v1 = *(const float4*)(T + lrow * 68 + c8 + 4);
    v0.x = fmaxf(v0.x + b0.x, 0.f); v0.y = fmaxf(v0.y + b0.y, 0.f);
    v0.z = fmaxf(v0.z + b0.z, 0.f); v0.w = fmaxf(v0.w + b0.w, 0.f);
    v1.x = fmaxf(v1.x + b1.x, 0.f); v1.y = fmaxf(v1.y + b1.y, 0.f);
    v1.z = fmaxf(v1.z + b1.z, 0.f); v1.w = fmaxf(v1.w + b1.w, 0.f);
    float* dst = a2c + (size_t)mm * HH + n0 + c8;
    *(float4*)dst       = v0;
    *(float4*)(dst + 4) = v1;
  }
}

__global__ __launch_bounds__(256) void k_actor(
    const float* __restrict__ a2c,
    const float* __restrict__ Wact, const float* __restrict__ bact,
    const float* __restrict__ Wcr, const float* __restrict__ bcr,
    float* __restrict__ out_pi, float* __restrict__ out_val) {
  const int b = blockIdx.x * 4 + (threadIdx.x >> 6);
  const int lane = threadIdx.x & 63;
  const float* hrow = a2c + (size_t)b * HH;
  float4 a0 = *(const float4*)(hrow + (lane << 3));
  float4 a1 = *(const float4*)(hrow + (lane << 3) + 4);
  float lg[17];
#pragma unroll
  for (int o = 0; o < 17; ++o) {
    const float* wr = (o < 16) ? (Wact + (size_t)o * HH) : Wcr;
    float4 w0 = *(const float4*)(wr + (lane << 3));
    float4 w1 = *(const float4*)(wr + (lane << 3) + 4);
    float s = a0.x * w0.x + a0.y * w0.y + a0.z * w0.z + a0.w * w0.w
            + a1.x * w1.x + a1.y * w1.y + a1.z * w1.z + a1.w * w1.w;
    lg[o] = waveReduceSum(s);
  }
#pragma unroll
  for (int o = 0; o < 16; ++o) lg[o] += bact[o];
  float mx = lg[0];
#pragma unroll
  for (int o = 1; o < 16; ++o) mx = fmaxf(mx, lg[o]);
  float e[16], sum = 0.f;
#pragma unroll
  for (int o = 0; o < 16; ++o) { e[o] = __expf(lg[o] - mx); sum += e[o]; }
  float rs = 1.f / sum;
  if (lane == 0) {
#pragma unroll
    for (int o = 0; o < 16; ++o) out_pi[(size_t)b * 16 + o] = e[o] * rs;
    out_val[b] = lg[16] + bcr[0];
  }
}

// ---------------- launch ----------------
extern "C" void kernel_launch(void* const* d_in, const int* in_sizes, int n_in,
                              void* d_out, int out_size, void* d_ws, size_t ws_size,
                              hipStream_t stream) {
  const float* x    = (const float*)d_in[0];
  const float* h    = (const float*)d_in[1];
  const float* c    = (const float*)d_in[2];
  const float* Wi   = (const float*)d_in[3];
  const float* bi   = (const float*)d_in[4];
  const float* Wh   = (const float*)d_in[5];
  const float* bh   = (const float*)d_in[6];
  const float* vals = (const float*)d_in[7];
  const float* Wih  = (const float*)d_in[8];
  const float* bih  = (const float*)d_in[9];
  const float* Wact = (const float*)d_in[10];
  const float* bact = (const float*)d_in[11];
  const float* Wcr  = (const float*)d_in[12];
  const float* bcr  = (const float*)d_in[13];
  const int*   mptr = (const int*)d_in[14];

  float* F = (float*)d_ws;
  __half* w_h    = (__half*)F;
  __half* sim_h   = (__half*)(F + 16777216);
  float*  a2c     = F + 16777216;
  __half* partial = (__half*)(F + 33554432);  // 8.4M halves (4 x 4096 x 512)
  float*  ct     = F + 50331648;
  float*  ot     = F + 52428800;
  __half* ct_h   = (__half*)(F + 54525952);
  __half* vals_h = (__half*)(F + 55574528);
  __half* vT_h   = (__half*)(F + 57671680);
  __half* x_h    = (__half*)(F + 59768832);
  __half* ht_h   = x_h;
  __half* h_h    = (__half*)(F + 60817408);
  __half* Wip_h  = (__half*)(F + 61865984);
  __half* Whp_h  = (__half*)(F + 62423040);
  __half* Wih_h  = (__half*)(F + 62980096);
  float*  inps   = F + 63111168;
  float*  leak   = inps + 4096;
  float*  comp   = leak + 4096;
  float*  rqn    = comp + 4096;
  float*  rmn    = rqn + 4096;

  float* out     = (float*)d_out;
  float* out_pi  = out;
  float* out_val = out + 65536;
  float* out_ht  = out + 69632;
  float* out_cmt = out_ht + 2097152;
  float* out_mt  = out_cmt + 2097152;
  float* out_nv  = out_mt + 2097152;

  (void)hipFuncSetAttribute(reinterpret_cast<const void*>(k_sim),
                            hipFuncAttributeMaxDynamicSharedMemorySize, 131072);

  dim3 b256(256);
  dim3 b512(512);
  k_prep   <<<12544, b256, 0, stream>>>(x, h, Wi, Wh, Wih, vals, mptr,
                                        x_h, h_h, Wip_h, Whp_h, Wih_h,
                                        out_nv, vals_h, rmn, vT_h);
  k_preact <<<dim3(16, 32), b256, 0, stream>>>(x_h, h_h, Wip_h, Whp_h, bi, bh, c,
                                               ct, ot, ct_h);
  k_scalars<<<BATCH, b256, 0, stream>>>(x, h, Wi, Wh, bi, bh, ct, inps, leak, comp, rqn);
  k_sim    <<<512, b512, 131072, stream>>>(ct_h, vals_h, rqn, rmn, sim_h);
  k_lca    <<<BATCH, b256, 0, stream>>>(sim_h, inps, leak, comp, w_h);
  k_mt_p   <<<1024, b256, 0, stream>>>(w_h, vT_h, partial);
  k_mt_red <<<2048, b256, 0, stream>>>(partial, ct, ot, mptr,
                                       out_mt, out_cmt, out_ht, out_nv, ht_h);
  k_a2c    <<<256, b256, 0, stream>>>(ht_h, Wih_h, bih, a2c);
  k_actor  <<<BATCH / 4, b256, 0, stream>>>(a2c, Wact, bact, Wcr, bcr, out_pi, out_val);
}